// Round 16
// baseline (159.205 us; speedup 1.0000x reference)
//
#include <hip/hip_runtime.h>

#define BB 8
#define CC 96
#define HH 224
#define WW 224

typedef _Float16 h2 __attribute__((ext_vector_type(2)));
typedef _Float16 v8h __attribute__((ext_vector_type(8)));
typedef float v4f __attribute__((ext_vector_type(4)));
__device__ __forceinline__ h2 u2h(unsigned u) { return __builtin_bit_cast(h2, u); }
__device__ __forceinline__ unsigned pkrtz(float a, float b) {
    return __builtin_bit_cast(unsigned, __builtin_amdgcn_cvt_pkrtz(a, b));
}

#if __has_builtin(__builtin_amdgcn_fdot2)
#define FDOT2(a, b, c) __builtin_amdgcn_fdot2((a), (b), (c), false)
#else
#define FDOT2(a, b, c) ((float)(a).x * (float)(b).x + (float)(a).y * (float)(b).y + (c))
#endif

// ---------------------------------------------------------------------------
// levels_fused2: ONE block per (b,c). Levels 1+2 AND reconstruction (ihaar2 +
// ihaar1) in LDS. Output: rec1 (B*C,112,56) packed fp16 h2. (unchanged)
// ---------------------------------------------------------------------------
__global__ __launch_bounds__(512, 4) void levels_fused2(
    const float* __restrict__ x,
    unsigned* __restrict__ rec1g,
    const float* __restrict__ wt1, const float* __restrict__ ws1,
    const float* __restrict__ wt2, const float* __restrict__ ws2)
{
    const int bc = blockIdx.x, c = bc % CC;
    const int t = threadIdx.x;

    __shared__ unsigned s_c1[112 * 58];
    __shared__ unsigned s_sb1[4 * 60 * 31];
    __shared__ unsigned s_cur2[56 * 30];
    __shared__ unsigned s_sb2[4 * 32 * 17];
    __shared__ unsigned s_w2[240];

    unsigned* const c1_01 = s_c1;
    unsigned* const c1_23 = s_c1 + 3192;
    unsigned* const c2_01 = s_cur2;
    unsigned* const c2_23 = s_cur2 + 812;
    float*    const rec2  = reinterpret_cast<float*>(s_sb1);

    for (int i = t; i < 4 * 60 * 31; i += 512) s_sb1[i] = 0;
    for (int i = t; i < 4 * 32 * 17; i += 512) s_sb2[i] = 0;

    if (t < 80) {
        int knl = t / 10;
        int par = t & 1, row = (t % 10) >> 1;
        int lvl = knl >> 2, s = knl & 3;
        const float* wt  = lvl ? wt2 : wt1;
        const float* wsc = lvl ? ws2 : ws1;
        float sc = 0.5f * wsc[c * 4 + s];
        float wv[5];
        #pragma unroll
        for (int j = 0; j < 5; ++j) wv[j] = wt[(c * 4 + s) * 25 + row * 5 + j] * sc;
        unsigned* dst = &s_w2[(knl * 2 + par) * 15 + row * 3];
        if (par == 0) {
            dst[0] = pkrtz(wv[0], wv[1]);
            dst[1] = pkrtz(wv[2], wv[3]);
            dst[2] = pkrtz(wv[4], 0.f);
        } else {
            dst[0] = pkrtz(0.f, wv[0]);
            dst[1] = pkrtz(wv[1], wv[2]);
            dst[2] = pkrtz(wv[3], wv[4]);
        }
    }

    const float* xp = x + (size_t)bc * HH * WW;
    for (int idx = t; idx < 112 * 56; idx += 512) {
        int r = idx / 56, g = idx % 56;
        const float* r0 = xp + (size_t)(2 * r) * WW + 4 * g;
        const float* r1 = r0 + WW;
        float4 a = *(const float4*)r0;
        float4 b = *(const float4*)r1;
        s_c1[r * 58 + g] = pkrtz(0.5f * (a.x + a.y + b.x + b.y),
                                 0.5f * (a.z + a.w + b.z + b.w));
    }
    __syncthreads();

    for (int idx = t; idx < 56 * 28; idx += 512) {
        int sr = idx / 28, sc2 = idx % 28;
        uint2 tp = *(const uint2*)&s_c1[(2 * sr) * 58 + 2 * sc2];
        uint2 bt = *(const uint2*)&s_c1[(2 * sr + 1) * 58 + 2 * sc2];
        h2 t0 = u2h(tp.x), t1 = u2h(tp.y), b0 = u2h(bt.x), b1 = u2h(bt.y);
        float P0 = (float)t0.x + (float)t0.y, M0 = (float)t0.x - (float)t0.y;
        float R0 = (float)b0.x + (float)b0.y, Q0 = (float)b0.x - (float)b0.y;
        float P1 = (float)t1.x + (float)t1.y, M1 = (float)t1.x - (float)t1.y;
        float R1 = (float)b1.x + (float)b1.y, Q1 = (float)b1.x - (float)b1.y;
        int o = (sr + 2) * 31 + (sc2 + 1);
        s_sb1[0 * 1860 + o] = pkrtz(P0 + R0, P1 + R1);
        s_sb1[1 * 1860 + o] = pkrtz(M0 + Q0, M1 + Q1);
        s_sb1[2 * 1860 + o] = pkrtz(P0 - R0, P1 - R1);
        s_sb1[3 * 1860 + o] = pkrtz(M0 - Q0, M1 - Q1);
        s_cur2[sr * 30 + sc2] = pkrtz(0.5f * (P0 + R0), 0.5f * (P1 + R1));
    }
    __syncthreads();

    if (t < 28 * 14) {
        int sr = t / 14, sc2 = t % 14;
        uint2 tp = *(const uint2*)&s_cur2[(2 * sr) * 30 + 2 * sc2];
        uint2 bt = *(const uint2*)&s_cur2[(2 * sr + 1) * 30 + 2 * sc2];
        h2 t0 = u2h(tp.x), t1 = u2h(tp.y), b0 = u2h(bt.x), b1 = u2h(bt.y);
        float P0 = (float)t0.x + (float)t0.y, M0 = (float)t0.x - (float)t0.y;
        float R0 = (float)b0.x + (float)b0.y, Q0 = (float)b0.x - (float)b0.y;
        float P1 = (float)t1.x + (float)t1.y, M1 = (float)t1.x - (float)t1.y;
        float R1 = (float)b1.x + (float)b1.y, Q1 = (float)b1.x - (float)b1.y;
        int o = (sr + 2) * 17 + (sc2 + 1);
        s_sb2[0 * 544 + o] = pkrtz(P0 + R0, P1 + R1);
        s_sb2[1 * 544 + o] = pkrtz(M0 + Q0, M1 + Q1);
        s_sb2[2 * 544 + o] = pkrtz(P0 - R0, P1 - R1);
        s_sb2[3 * 544 + o] = pkrtz(M0 - Q0, M1 - Q1);
    }

    {
        const int s = t >> 7, lane = t & 127;
        const int q = lane & 63, half = lane >> 6;
        if (q < 56) {
            const int par = q & 1, d0 = q >> 1, ps = half * 28;
            h2 w[5][3];
            {
                const unsigned* wp = &s_w2[(s * 2 + par) * 15];
                #pragma unroll
                for (int ki = 0; ki < 5; ++ki)
                    #pragma unroll
                    for (int m = 0; m < 3; ++m) w[ki][m] = u2h(wp[ki * 3 + m]);
            }
            float acc[28];
            #pragma unroll
            for (int r = 0; r < 28; ++r) acc[r] = 0.f;
            #pragma unroll
            for (int ri = 0; ri < 32; ++ri) {
                const unsigned* rp = &s_sb1[s * 1860 + (ps + ri) * 31 + d0];
                h2 g0 = u2h(rp[0]), g1 = u2h(rp[1]), g2 = u2h(rp[2]);
                #pragma unroll
                for (int ki = 0; ki < 5; ++ki) {
                    int r = ri - ki;
                    if (r >= 0 && r < 28)
                        acc[r] = FDOT2(g0, w[ki][0],
                                 FDOT2(g1, w[ki][1],
                                 FDOT2(g2, w[ki][2], acc[r])));
                }
            }
            _Float16* dstH = reinterpret_cast<_Float16*>((s < 2) ? c1_01 : c1_23);
            const int hf = s & 1;
            #pragma unroll
            for (int r = 0; r < 28; ++r)
                dstH[((ps + r) * 57 + q) * 2 + hf] = (_Float16)acc[r];
        }
    }
    __syncthreads();

    if (t < 112) {
        const int s = t / 28, q = t % 28;
        const int par = q & 1, d0 = q >> 1;
        h2 w[5][3];
        {
            const unsigned* wp = &s_w2[((4 + s) * 2 + par) * 15];
            #pragma unroll
            for (int ki = 0; ki < 5; ++ki)
                #pragma unroll
                for (int m = 0; m < 3; ++m) w[ki][m] = u2h(wp[ki * 3 + m]);
        }
        float acc[28];
        #pragma unroll
        for (int r = 0; r < 28; ++r) acc[r] = 0.f;
        #pragma unroll
        for (int ri = 0; ri < 32; ++ri) {
            const unsigned* rp = &s_sb2[s * 544 + ri * 17 + d0];
            h2 g0 = u2h(rp[0]), g1 = u2h(rp[1]), g2 = u2h(rp[2]);
            #pragma unroll
            for (int ki = 0; ki < 5; ++ki) {
                int r = ri - ki;
                if (r >= 0 && r < 28)
                    acc[r] = FDOT2(g0, w[ki][0],
                             FDOT2(g1, w[ki][1],
                             FDOT2(g2, w[ki][2], acc[r])));
            }
        }
        _Float16* dstH = reinterpret_cast<_Float16*>((s < 2) ? c2_01 : c2_23);
        const int hf = s & 1;
        #pragma unroll
        for (int r = 0; r < 28; ++r)
            dstH[(r * 29 + q) * 2 + hf] = (_Float16)acc[r];
    }
    __syncthreads();

    for (int i = t; i < 784; i += 512) {
        int p2 = i / 28, q2 = i % 28;
        h2 v01 = u2h(c2_01[p2 * 29 + q2]);
        h2 v23 = u2h(c2_23[p2 * 29 + q2]);
        float ll = v01.x, lh = v01.y, hl = v23.x, hh = v23.y;
        float a  = 0.5f * (ll + lh + hl + hh);
        float b  = 0.5f * (ll - lh + hl - hh);
        float cv = 0.5f * (ll + lh - hl - hh);
        float d  = 0.5f * (ll - lh - hl + hh);
        float* rp = &rec2[(2 * p2) * 57 + 2 * q2];
        rp[0] = a; rp[1] = b; rp[57] = cv; rp[58] = d;
    }
    __syncthreads();

    unsigned* rg = rec1g + (size_t)bc * 112 * 56;
    for (int i = t; i < 3136; i += 512) {
        int p1 = i / 56, q1 = i % 56;
        h2 v01 = u2h(c1_01[p1 * 57 + q1]);
        h2 v23 = u2h(c1_23[p1 * 57 + q1]);
        float ll = (float)v01.x + rec2[p1 * 57 + q1];
        float lh = v01.y, hl = v23.x, hh = v23.y;
        float a  = 0.5f * (ll + lh + hl + hh);
        float b  = 0.5f * (ll - lh + hl - hh);
        float cv = 0.5f * (ll + lh - hl - hh);
        float d  = 0.5f * (ll - lh - hl + hh);
        rg[(size_t)(2 * p1) * 56 + q1]     = pkrtz(a, b);
        rg[(size_t)(2 * p1 + 1) * 56 + q1] = pkrtz(cv, d);
    }
}

// ---------------------------------------------------------------------------
// final_mfma: base conv + L0 subband convs via MFMA (banded-Toeplitz B).
// Block = 32x224 output stripe, grid (7, 768), 256 thr = 4 waves.
// FIX vs R14: base-conv A row needs +2 (s_x has a 4-row halo; conv taps
// start at output_row - 2 = s_x row rt*16 + m + ki + 2).
// ---------------------------------------------------------------------------
__global__ __launch_bounds__(256, 3) void final_mfma(
    const float* __restrict__ x,
    const float* __restrict__ bw,
    const float* __restrict__ bb,
    const float* __restrict__ bs,
    const float* __restrict__ wt0,
    const float* __restrict__ wsc0,
    const unsigned* __restrict__ rec1g,  // (B*C,112,56) h2
    float* __restrict__ out)
{
    const int sy = blockIdx.x;              // out rows 32sy .. 32sy+31
    const int bc = blockIdx.y, c = bc % CC;
    const int t = threadIdx.x;
    const int lane = t & 63, w = t >> 6;

    __shared__ unsigned s_x[40 * 122];      // fp16 [40][244], x col g -> fp16 col g+6
    __shared__ unsigned s_sb[4 * 20 * 66];  // fp16 [band][20][132], sb col q -> fp16 q+2
    __shared__ unsigned s_rec[16 * 57];     // packed h2 rec1 tile
    __shared__ float s_wb[25];
    __shared__ float s_ws[4 * 25];
    unsigned* const cv01 = s_x;             // overlay: [16][113] dw
    unsigned* const cv23 = s_x + 16 * 113;  // overlay: [16][113]
    unsigned* const s_bc = s_sb;            // overlay: [32][113] dw

    for (int i = t; i < 40 * 122; i += 256) s_x[i] = 0;
    for (int i = t; i < 4 * 20 * 66; i += 256) s_sb[i] = 0;

    if (t < 25) s_wb[t] = bw[c * 25 + t] * bs[c];
    if (t >= 32 && t < 132) {
        int s = (t - 32) / 25, k = (t - 32) % 25;
        s_ws[s * 25 + k] = wt0[(c * 4 + s) * 25 + k] * 0.5f * wsc0[c * 4 + s];
    }

    for (int idx = t; idx < 896; idx += 256) {
        int r = idx / 56, d = idx % 56;
        s_rec[r * 57 + d] = rec1g[((size_t)bc * 112 + 16 * sy + r) * 56 + d];
    }

    const float* xp = x + (size_t)bc * HH * WW;
    for (int idx = t; idx < 2240; idx += 256) {
        int r = idx / 56, f = idx % 56;
        int gr = 32 * sy - 4 + r;
        if ((unsigned)gr < HH) {
            float4 v = *(const float4*)(xp + (size_t)gr * WW + 4 * f);
            unsigned* dp = &s_x[r * 122 + 2 * f + 3];
            dp[0] = pkrtz(v.x, v.y);
            dp[1] = pkrtz(v.z, v.w);
        }
    }
    __syncthreads();

    for (int idx = t; idx < 1160; idx += 256) {
        int pp = idx / 58, q2 = idx % 58;
        const unsigned* r0p = &s_x[(2 * pp) * 122 + 2 * q2 + 1];
        const unsigned* r1p = &s_x[(2 * pp + 1) * 122 + 2 * q2 + 1];
        h2 t0 = u2h(r0p[0]), t1 = u2h(r0p[1]);
        h2 b0 = u2h(r1p[0]), b1 = u2h(r1p[1]);
        float P0 = (float)t0.x + (float)t0.y, M0 = (float)t0.x - (float)t0.y;
        float R0 = (float)b0.x + (float)b0.y, Q0 = (float)b0.x - (float)b0.y;
        float P1 = (float)t1.x + (float)t1.y, M1 = (float)t1.x - (float)t1.y;
        float R1 = (float)b1.x + (float)b1.y, Q1 = (float)b1.x - (float)b1.y;
        int o = pp * 66 + q2;
        s_sb[0 * 1320 + o] = pkrtz(P0 + R0, P1 + R1);
        s_sb[1 * 1320 + o] = pkrtz(M0 + Q0, M1 + Q1);
        s_sb[2 * 1320 + o] = pkrtz(P0 - R0, P1 - R1);
        s_sb[3 * 1320 + o] = pkrtz(M0 - Q0, M1 - Q1);
    }

    // ---- base conv via mfma ----
    const int nB = lane & 15, hB = lane >> 4;
    v4f bcc[7];
    {
        v8h bfr[5];
        #pragma unroll
        for (int ki = 0; ki < 5; ++ki) {
            v8h f;
            #pragma unroll
            for (int j = 0; j < 8; ++j) {
                int d = 8 * hB + j - nB;
                f[j] = (_Float16)((d >= 0 && d < 5) ? s_wb[ki * 5 + d] : 0.f);
            }
            bfr[ki] = f;
        }
        const int rt = w >> 1;
        #pragma unroll
        for (int i = 0; i < 7; ++i) {
            int ct = (w & 1) * 7 + i;
            v4f acc = {0.f, 0.f, 0.f, 0.f};
            #pragma unroll
            for (int ki = 0; ki < 5; ++ki) {
                int arow = rt * 16 + ki + nB + 2;   // FIX: +2 halo offset
                const unsigned* ap = &s_x[arow * 122 + 8 * ct + 2 + 4 * hB];
                uint2 lo = *(const uint2*)ap;
                uint2 hi = *(const uint2*)(ap + 2);
                union { uint2 u2[2]; v8h v; } cvt;
                cvt.u2[0] = lo; cvt.u2[1] = hi;
                acc = __builtin_amdgcn_mfma_f32_16x16x32_f16(cvt.v, bfr[ki], acc, 0, 0, 0);
            }
            bcc[i] = acc;
        }
    }
    __syncthreads();

    // ---- subband conv via mfma: wave w = band w, 7 col-tiles ----
    v4f scc[7];
    {
        v8h sfr[5];
        #pragma unroll
        for (int ki = 0; ki < 5; ++ki) {
            v8h f;
            #pragma unroll
            for (int j = 0; j < 8; ++j) {
                int d = 8 * hB + j - nB;
                f[j] = (_Float16)((d >= 0 && d < 5) ? s_ws[w * 25 + ki * 5 + d] : 0.f);
            }
            sfr[ki] = f;
        }
        #pragma unroll
        for (int i = 0; i < 7; ++i) {
            v4f acc = {0.f, 0.f, 0.f, 0.f};
            #pragma unroll
            for (int ki = 0; ki < 5; ++ki) {
                int arow = ki + nB;
                const unsigned* ap = &s_sb[w * 1320 + arow * 66 + 8 * i + 4 * hB];
                uint2 lo = *(const uint2*)ap;
                uint2 hi = *(const uint2*)(ap + 2);
                union { uint2 u2[2]; v8h v; } cvt;
                cvt.u2[0] = lo; cvt.u2[1] = hi;
                acc = __builtin_amdgcn_mfma_f32_16x16x32_f16(cvt.v, sfr[ki], acc, 0, 0, 0);
            }
            scc[i] = acc;
        }
    }
    __syncthreads();

    // ---- dump base C -> s_bc (fp16), sb C -> cv01/cv23 halves ----
    {
        _Float16* bc16 = reinterpret_cast<_Float16*>(s_bc);
        const int rt = w >> 1;
        #pragma unroll
        for (int i = 0; i < 7; ++i) {
            int col = ((w & 1) * 7 + i) * 16 + nB;
            #pragma unroll
            for (int reg = 0; reg < 4; ++reg) {
                int row = rt * 16 + 4 * hB + reg;
                bc16[row * 226 + col] = (_Float16)bcc[i][reg];
            }
        }
        _Float16* cv16 = reinterpret_cast<_Float16*>((w < 2) ? cv01 : cv23);
        const int hf = w & 1;
        #pragma unroll
        for (int i = 0; i < 7; ++i) {
            int col = i * 16 + nB;
            #pragma unroll
            for (int reg = 0; reg < 4; ++reg) {
                int row = 4 * hB + reg;
                cv16[(row * 113 + col) * 2 + hf] = (_Float16)scc[i][reg];
            }
        }
    }
    __syncthreads();

    // ---- combine: ihaar0 + base + bias, float2 stores ----
    {
        const float bbv = bb[c];
        #pragma unroll
        for (int it = 0; it < 7; ++it) {
            int idx = t + it * 256;
            int p = idx / 112, qq = idx % 112;
            h2 v01 = u2h(cv01[p * 113 + qq]);
            h2 v23 = u2h(cv23[p * 113 + qq]);
            h2 rr  = u2h(s_rec[p * 57 + (qq >> 1)]);
            float ll = (float)v01.x + (float)((qq & 1) ? rr.y : rr.x);
            float lh = v01.y, hl = v23.x, hh = v23.y;
            float a  = 0.5f * (ll + lh + hl + hh);
            float b2 = 0.5f * (ll - lh + hl - hh);
            float cv = 0.5f * (ll + lh - hl - hh);
            float d  = 0.5f * (ll - lh - hl + hh);
            h2 bt = u2h(s_bc[(2 * p) * 113 + qq]);
            h2 bm = u2h(s_bc[(2 * p + 1) * 113 + qq]);
            float* op = out + ((size_t)bc * HH + 32 * sy + 2 * p) * WW + 2 * qq;
            *(float2*)op        = make_float2(a + (float)bt.x + bbv, b2 + (float)bt.y + bbv);
            *(float2*)(op + WW) = make_float2(cv + (float)bm.x + bbv, d + (float)bm.y + bbv);
        }
    }
}

extern "C" void kernel_launch(void* const* d_in, const int* in_sizes, int n_in,
                              void* d_out, int out_size, void* d_ws, size_t ws_size,
                              hipStream_t stream) {
    const float* x          = (const float*)d_in[0];
    const float* base_w     = (const float*)d_in[1];
    const float* base_b     = (const float*)d_in[2];
    const float* base_scale = (const float*)d_in[3];
    const float* wconv_w    = (const float*)d_in[4]; // (3, 384, 25)
    const float* wscale     = (const float*)d_in[5]; // (3, 384)
    float* out = (float*)d_out;
    unsigned* rec1 = (unsigned*)d_ws;   // (B*C,112,56) h2 dwords

    const int z = BB * CC;

    // levels 1+2 + reconstruction; writes rec1 only
    levels_fused2<<<z, 512, 0, stream>>>(
        x, rec1,
        wconv_w + 1 * 384 * 25, wscale + 1 * 384,
        wconv_w + 2 * 384 * 25, wscale + 2 * 384);
    // final: MFMA convs + combine
    final_mfma<<<dim3(7, z), 256, 0, stream>>>(
        x, base_w, base_b, base_scale,
        wconv_w + 0 * 384 * 25, wscale + 0 * 384, rec1, out);
}

// Round 17
// 132.687 us; speedup vs baseline: 1.1999x; 1.1999x over previous
//
#include <hip/hip_runtime.h>

#define BB 8
#define CC 96
#define HH 224
#define WW 224

typedef _Float16 h2 __attribute__((ext_vector_type(2)));
__device__ __forceinline__ h2 u2h(unsigned u) { return __builtin_bit_cast(h2, u); }
__device__ __forceinline__ unsigned pkrtz(float a, float b) {
    return __builtin_bit_cast(unsigned, __builtin_amdgcn_cvt_pkrtz(a, b));
}

#if __has_builtin(__builtin_amdgcn_fdot2)
#define FDOT2(a, b, c) __builtin_amdgcn_fdot2((a), (b), (c), false)
#else
#define FDOT2(a, b, c) ((float)(a).x * (float)(b).x + (float)(a).y * (float)(b).y + (c))
#endif

// ---------------------------------------------------------------------------
// levels_fused2: ONE block per (b,c). Levels 1+2 AND reconstruction (ihaar2 +
// ihaar1) in LDS. Output: rec1 (B*C,112,56) packed fp16 h2. (unchanged)
// ---------------------------------------------------------------------------
__global__ __launch_bounds__(512, 4) void levels_fused2(
    const float* __restrict__ x,
    unsigned* __restrict__ rec1g,
    const float* __restrict__ wt1, const float* __restrict__ ws1,
    const float* __restrict__ wt2, const float* __restrict__ ws2)
{
    const int bc = blockIdx.x, c = bc % CC;
    const int t = threadIdx.x;

    __shared__ unsigned s_c1[112 * 58];
    __shared__ unsigned s_sb1[4 * 60 * 31];
    __shared__ unsigned s_cur2[56 * 30];
    __shared__ unsigned s_sb2[4 * 32 * 17];
    __shared__ unsigned s_w2[240];

    unsigned* const c1_01 = s_c1;
    unsigned* const c1_23 = s_c1 + 3192;
    unsigned* const c2_01 = s_cur2;
    unsigned* const c2_23 = s_cur2 + 812;
    float*    const rec2  = reinterpret_cast<float*>(s_sb1);

    for (int i = t; i < 4 * 60 * 31; i += 512) s_sb1[i] = 0;
    for (int i = t; i < 4 * 32 * 17; i += 512) s_sb2[i] = 0;

    if (t < 80) {
        int knl = t / 10;
        int par = t & 1, row = (t % 10) >> 1;
        int lvl = knl >> 2, s = knl & 3;
        const float* wt  = lvl ? wt2 : wt1;
        const float* wsc = lvl ? ws2 : ws1;
        float sc = 0.5f * wsc[c * 4 + s];
        float wv[5];
        #pragma unroll
        for (int j = 0; j < 5; ++j) wv[j] = wt[(c * 4 + s) * 25 + row * 5 + j] * sc;
        unsigned* dst = &s_w2[(knl * 2 + par) * 15 + row * 3];
        if (par == 0) {
            dst[0] = pkrtz(wv[0], wv[1]);
            dst[1] = pkrtz(wv[2], wv[3]);
            dst[2] = pkrtz(wv[4], 0.f);
        } else {
            dst[0] = pkrtz(0.f, wv[0]);
            dst[1] = pkrtz(wv[1], wv[2]);
            dst[2] = pkrtz(wv[3], wv[4]);
        }
    }

    const float* xp = x + (size_t)bc * HH * WW;
    for (int idx = t; idx < 112 * 56; idx += 512) {
        int r = idx / 56, g = idx % 56;
        const float* r0 = xp + (size_t)(2 * r) * WW + 4 * g;
        const float* r1 = r0 + WW;
        float4 a = *(const float4*)r0;
        float4 b = *(const float4*)r1;
        s_c1[r * 58 + g] = pkrtz(0.5f * (a.x + a.y + b.x + b.y),
                                 0.5f * (a.z + a.w + b.z + b.w));
    }
    __syncthreads();

    for (int idx = t; idx < 56 * 28; idx += 512) {
        int sr = idx / 28, sc2 = idx % 28;
        uint2 tp = *(const uint2*)&s_c1[(2 * sr) * 58 + 2 * sc2];
        uint2 bt = *(const uint2*)&s_c1[(2 * sr + 1) * 58 + 2 * sc2];
        h2 t0 = u2h(tp.x), t1 = u2h(tp.y), b0 = u2h(bt.x), b1 = u2h(bt.y);
        float P0 = (float)t0.x + (float)t0.y, M0 = (float)t0.x - (float)t0.y;
        float R0 = (float)b0.x + (float)b0.y, Q0 = (float)b0.x - (float)b0.y;
        float P1 = (float)t1.x + (float)t1.y, M1 = (float)t1.x - (float)t1.y;
        float R1 = (float)b1.x + (float)b1.y, Q1 = (float)b1.x - (float)b1.y;
        int o = (sr + 2) * 31 + (sc2 + 1);
        s_sb1[0 * 1860 + o] = pkrtz(P0 + R0, P1 + R1);
        s_sb1[1 * 1860 + o] = pkrtz(M0 + Q0, M1 + Q1);
        s_sb1[2 * 1860 + o] = pkrtz(P0 - R0, P1 - R1);
        s_sb1[3 * 1860 + o] = pkrtz(M0 - Q0, M1 - Q1);
        s_cur2[sr * 30 + sc2] = pkrtz(0.5f * (P0 + R0), 0.5f * (P1 + R1));
    }
    __syncthreads();

    if (t < 28 * 14) {
        int sr = t / 14, sc2 = t % 14;
        uint2 tp = *(const uint2*)&s_cur2[(2 * sr) * 30 + 2 * sc2];
        uint2 bt = *(const uint2*)&s_cur2[(2 * sr + 1) * 30 + 2 * sc2];
        h2 t0 = u2h(tp.x), t1 = u2h(tp.y), b0 = u2h(bt.x), b1 = u2h(bt.y);
        float P0 = (float)t0.x + (float)t0.y, M0 = (float)t0.x - (float)t0.y;
        float R0 = (float)b0.x + (float)b0.y, Q0 = (float)b0.x - (float)b0.y;
        float P1 = (float)t1.x + (float)t1.y, M1 = (float)t1.x - (float)t1.y;
        float R1 = (float)b1.x + (float)b1.y, Q1 = (float)b1.x - (float)b1.y;
        int o = (sr + 2) * 17 + (sc2 + 1);
        s_sb2[0 * 544 + o] = pkrtz(P0 + R0, P1 + R1);
        s_sb2[1 * 544 + o] = pkrtz(M0 + Q0, M1 + Q1);
        s_sb2[2 * 544 + o] = pkrtz(P0 - R0, P1 - R1);
        s_sb2[3 * 544 + o] = pkrtz(M0 - Q0, M1 - Q1);
    }

    {
        const int s = t >> 7, lane = t & 127;
        const int q = lane & 63, half = lane >> 6;
        if (q < 56) {
            const int par = q & 1, d0 = q >> 1, ps = half * 28;
            h2 w[5][3];
            {
                const unsigned* wp = &s_w2[(s * 2 + par) * 15];
                #pragma unroll
                for (int ki = 0; ki < 5; ++ki)
                    #pragma unroll
                    for (int m = 0; m < 3; ++m) w[ki][m] = u2h(wp[ki * 3 + m]);
            }
            float acc[28];
            #pragma unroll
            for (int r = 0; r < 28; ++r) acc[r] = 0.f;
            #pragma unroll
            for (int ri = 0; ri < 32; ++ri) {
                const unsigned* rp = &s_sb1[s * 1860 + (ps + ri) * 31 + d0];
                h2 g0 = u2h(rp[0]), g1 = u2h(rp[1]), g2 = u2h(rp[2]);
                #pragma unroll
                for (int ki = 0; ki < 5; ++ki) {
                    int r = ri - ki;
                    if (r >= 0 && r < 28)
                        acc[r] = FDOT2(g0, w[ki][0],
                                 FDOT2(g1, w[ki][1],
                                 FDOT2(g2, w[ki][2], acc[r])));
                }
            }
            _Float16* dstH = reinterpret_cast<_Float16*>((s < 2) ? c1_01 : c1_23);
            const int hf = s & 1;
            #pragma unroll
            for (int r = 0; r < 28; ++r)
                dstH[((ps + r) * 57 + q) * 2 + hf] = (_Float16)acc[r];
        }
    }
    __syncthreads();

    if (t < 112) {
        const int s = t / 28, q = t % 28;
        const int par = q & 1, d0 = q >> 1;
        h2 w[5][3];
        {
            const unsigned* wp = &s_w2[((4 + s) * 2 + par) * 15];
            #pragma unroll
            for (int ki = 0; ki < 5; ++ki)
                #pragma unroll
                for (int m = 0; m < 3; ++m) w[ki][m] = u2h(wp[ki * 3 + m]);
        }
        float acc[28];
        #pragma unroll
        for (int r = 0; r < 28; ++r) acc[r] = 0.f;
        #pragma unroll
        for (int ri = 0; ri < 32; ++ri) {
            const unsigned* rp = &s_sb2[s * 544 + ri * 17 + d0];
            h2 g0 = u2h(rp[0]), g1 = u2h(rp[1]), g2 = u2h(rp[2]);
            #pragma unroll
            for (int ki = 0; ki < 5; ++ki) {
                int r = ri - ki;
                if (r >= 0 && r < 28)
                    acc[r] = FDOT2(g0, w[ki][0],
                             FDOT2(g1, w[ki][1],
                             FDOT2(g2, w[ki][2], acc[r])));
            }
        }
        _Float16* dstH = reinterpret_cast<_Float16*>((s < 2) ? c2_01 : c2_23);
        const int hf = s & 1;
        #pragma unroll
        for (int r = 0; r < 28; ++r)
            dstH[(r * 29 + q) * 2 + hf] = (_Float16)acc[r];
    }
    __syncthreads();

    for (int i = t; i < 784; i += 512) {
        int p2 = i / 28, q2 = i % 28;
        h2 v01 = u2h(c2_01[p2 * 29 + q2]);
        h2 v23 = u2h(c2_23[p2 * 29 + q2]);
        float ll = v01.x, lh = v01.y, hl = v23.x, hh = v23.y;
        float a  = 0.5f * (ll + lh + hl + hh);
        float b  = 0.5f * (ll - lh + hl - hh);
        float cv = 0.5f * (ll + lh - hl - hh);
        float d  = 0.5f * (ll - lh - hl + hh);
        float* rp = &rec2[(2 * p2) * 57 + 2 * q2];
        rp[0] = a; rp[1] = b; rp[57] = cv; rp[58] = d;
    }
    __syncthreads();

    unsigned* rg = rec1g + (size_t)bc * 112 * 56;
    for (int i = t; i < 3136; i += 512) {
        int p1 = i / 56, q1 = i % 56;
        h2 v01 = u2h(c1_01[p1 * 57 + q1]);
        h2 v23 = u2h(c1_23[p1 * 57 + q1]);
        float ll = (float)v01.x + rec2[p1 * 57 + q1];
        float lh = v01.y, hl = v23.x, hh = v23.y;
        float a  = 0.5f * (ll + lh + hl + hh);
        float b  = 0.5f * (ll - lh + hl - hh);
        float cv = 0.5f * (ll + lh - hl - hh);
        float d  = 0.5f * (ll - lh - hl + hh);
        rg[(size_t)(2 * p1) * 56 + q1]     = pkrtz(a, b);
        rg[(size_t)(2 * p1 + 1) * 56 + q1] = pkrtz(cv, d);
    }
}

// ---------------------------------------------------------------------------
// final_fused_v11: v10 core (fp16 LDS + fdot2, 256 thr, 56x56 tile) with
// packed band-pair cv layout (cv01/cv23 dwords) from v8 — phase-4 reads
// 2 dwords instead of 4 scalar b16 per output.
// ---------------------------------------------------------------------------
__global__ __launch_bounds__(256, 7) void final_fused_v11(
    const float* __restrict__ x,
    const float* __restrict__ bw,
    const float* __restrict__ bb,
    const float* __restrict__ bs,
    const float* __restrict__ wt0,
    const float* __restrict__ wsc0,
    const unsigned* __restrict__ rec1g,  // (B*C,112,56) h2
    float* __restrict__ out)
{
    const int bc = blockIdx.z, c = bc % CC;
    const int t = threadIdx.x;

    __shared__ unsigned s_x2[64 * 34];   // h2 x-tile; phase>=3: cv01/cv23 overlay
    __shared__ unsigned s_sb[4 * 544];   // h2 subbands, stride 17
    __shared__ float s_rec1[28 * 29];
    __shared__ unsigned s_w2[150];
    unsigned* const s_cv01 = s_x2;        // [28][29] dw (band0 lo, band1 hi)
    unsigned* const s_cv23 = s_x2 + 812;  // [28][29] dw (band2 lo, band3 hi)

    if (t < 50) {
        int par = t & 1, row = (t >> 1) % 5, knl = t / 10;
        float wv[5];
        if (knl == 0) {
            float sc = bs[c];
            #pragma unroll
            for (int j = 0; j < 5; ++j) wv[j] = bw[c * 25 + row * 5 + j] * sc;
        } else {
            int s = knl - 1;
            float sc = 0.5f * wsc0[c * 4 + s];
            #pragma unroll
            for (int j = 0; j < 5; ++j) wv[j] = wt0[(c * 4 + s) * 25 + row * 5 + j] * sc;
        }
        unsigned* dst = &s_w2[((knl * 2 + par) * 5 + row) * 3];
        if (par == 0) {
            dst[0] = pkrtz(wv[0], wv[1]);
            dst[1] = pkrtz(wv[2], wv[3]);
            dst[2] = pkrtz(wv[4], 0.f);
        } else {
            dst[0] = pkrtz(0.f, wv[0]);
            dst[1] = pkrtz(wv[1], wv[2]);
            dst[2] = pkrtz(wv[3], wv[4]);
        }
    }

    // ---- rec1 tile load (392 dwords; 2 per thread for t<196) ----
    if (t < 196) {
        #pragma unroll
        for (int k = 0; k < 2; ++k) {
            int idx = 2 * t + k;
            int r = idx / 14, d = idx % 14;
            unsigned v = rec1g[((size_t)bc * 112 + 28 * blockIdx.y + r) * 56
                               + 14 * blockIdx.x + d];
            h2 hv = u2h(v);
            s_rec1[r * 29 + 2 * d]     = hv.x;
            s_rec1[r * 29 + 2 * d + 1] = hv.y;
        }
    }

    // ---- phase 1: stage 64x64 x-tile as packed fp16 ----
    const float* xp = x + (size_t)bc * HH * WW;
    const int gy0 = 56 * blockIdx.y - 4, gx0 = 56 * blockIdx.x - 4;
    for (int idx = t; idx < 1024; idx += 256) {
        int r = idx >> 4, j = idx & 15;
        int gr = gy0 + r, gc = gx0 + 4 * j;
        float4 v = make_float4(0.f, 0.f, 0.f, 0.f);
        if (gr >= 0 && gr < HH && gc >= 0 && gc + 3 < WW)
            v = *(const float4*)(xp + (size_t)gr * WW + gc);
        uint2 pp;
        pp.x = pkrtz(v.x, v.y);
        pp.y = pkrtz(v.z, v.w);
        *(uint2*)&s_x2[r * 34 + 2 * j] = pp;
    }
    __syncthreads();

    // ---- phase 2a: haar butterfly (unscaled) ----
    for (int idx = t; idx < 512; idx += 256) {
        int sr = idx >> 4, g = idx & 15;
        uint2 tp = *(const uint2*)&s_x2[(2 * sr) * 34 + 2 * g];
        uint2 bt = *(const uint2*)&s_x2[(2 * sr + 1) * 34 + 2 * g];
        h2 t0 = u2h(tp.x), t1 = u2h(tp.y), b0 = u2h(bt.x), b1 = u2h(bt.y);
        float a0 = t0.x, e0 = t0.y, cc0 = b0.x, f0 = b0.y;
        float a1 = t1.x, e1 = t1.y, cc1 = b1.x, f1 = b1.y;
        float P0 = a0 + e0, M0 = a0 - e0, R0 = cc0 + f0, Q0 = cc0 - f0;
        float P1 = a1 + e1, M1 = a1 - e1, R1 = cc1 + f1, Q1 = cc1 - f1;
        s_sb[0 * 544 + sr * 17 + g] = pkrtz(P0 + R0, P1 + R1);
        s_sb[1 * 544 + sr * 17 + g] = pkrtz(M0 + Q0, M1 + Q1);
        s_sb[2 * 544 + sr * 17 + g] = pkrtz(P0 - R0, P1 - R1);
        s_sb[3 * 544 + sr * 17 + g] = pkrtz(M0 - Q0, M1 - Q1);
    }

    // ---- phase 2b: base conv via fdot2 (bacc in regs) ----
    const int q4 = t % 56, rb4 = t / 56;
    float bacc[14];
    if (t < 224) {
        const int par = q4 & 1, d0 = (q4 + 2) >> 1;
        h2 w[5][3];
        {
            const unsigned* wp = &s_w2[(par * 5) * 3];
            #pragma unroll
            for (int ki = 0; ki < 5; ++ki)
                #pragma unroll
                for (int m = 0; m < 3; ++m) w[ki][m] = u2h(wp[ki * 3 + m]);
        }
        #pragma unroll
        for (int r = 0; r < 14; ++r) bacc[r] = 0.f;
        #pragma unroll
        for (int ri = 0; ri < 18; ++ri) {
            const unsigned* rp = &s_x2[(rb4 * 14 + ri + 2) * 34 + d0];
            h2 g0 = u2h(rp[0]), g1 = u2h(rp[1]), g2 = u2h(rp[2]);
            #pragma unroll
            for (int ki = 0; ki < 5; ++ki) {
                int r = ri - ki;
                if (r >= 0 && r < 14)
                    bacc[r] = FDOT2(g0, w[ki][0],
                              FDOT2(g1, w[ki][1],
                              FDOT2(g2, w[ki][2], bacc[r])));
            }
        }
    }
    __syncthreads();

    // ---- phase 3: subband convs -> packed cv01/cv23 (overlay on s_x2) ----
    {
        const int s = t >> 6, u = t & 63;
        if (u < 56) {
            const int q = u % 28, rb = u / 28;
            const int par = q & 1, d0 = q >> 1;
            h2 w[5][3];
            {
                const unsigned* wp = &s_w2[(((1 + s) * 2 + par) * 5) * 3];
                #pragma unroll
                for (int ki = 0; ki < 5; ++ki)
                    #pragma unroll
                    for (int m = 0; m < 3; ++m) w[ki][m] = u2h(wp[ki * 3 + m]);
            }
            float acc[14];
            #pragma unroll
            for (int r = 0; r < 14; ++r) acc[r] = 0.f;
            #pragma unroll
            for (int ri = 0; ri < 18; ++ri) {
                const unsigned* rp = &s_sb[s * 544 + (rb * 14 + ri) * 17 + d0];
                h2 g0 = u2h(rp[0]), g1 = u2h(rp[1]), g2 = u2h(rp[2]);
                #pragma unroll
                for (int ki = 0; ki < 5; ++ki) {
                    int r = ri - ki;
                    if (r >= 0 && r < 14)
                        acc[r] = FDOT2(g0, w[ki][0],
                                 FDOT2(g1, w[ki][1],
                                 FDOT2(g2, w[ki][2], acc[r])));
                }
            }
            _Float16* base16 = reinterpret_cast<_Float16*>((s < 2) ? s_cv01 : s_cv23);
            const int hf = s & 1;
            #pragma unroll
            for (int r = 0; r < 14; ++r)
                base16[((rb * 14 + r) * 29 + q) * 2 + hf] = (_Float16)acc[r];
        }
    }
    __syncthreads();

    // ---- phase 4: ihaar level 0 (packed reads) + base + store ----
    if (t < 224) {
        const float bbv = bb[c];
        const int qs = q4 >> 1;
        const float sx = (q4 & 1) ? -1.f : 1.f;
        float* op = out + ((size_t)bc * HH + 56 * blockIdx.y + rb4 * 14) * WW
                        + 56 * blockIdx.x + q4;
        #pragma unroll
        for (int j = 0; j < 7; ++j) {
            const int p = rb4 * 7 + j;
            h2 v01 = u2h(s_cv01[p * 29 + qs]);
            h2 v23 = u2h(s_cv23[p * 29 + qs]);
            float ll = (float)v01.x + s_rec1[p * 29 + qs];
            float lh = v01.y;
            float hl = v23.x;
            float hh = v23.y;
            float e0 = ll + sx * lh;
            float e1 = hl + sx * hh;
            float top = 0.5f * (e0 + e1);
            float bot = 0.5f * (e0 - e1);
            op[(size_t)(2 * j) * WW]     = bacc[2 * j]     + bbv + top;
            op[(size_t)(2 * j + 1) * WW] = bacc[2 * j + 1] + bbv + bot;
        }
    }
}

extern "C" void kernel_launch(void* const* d_in, const int* in_sizes, int n_in,
                              void* d_out, int out_size, void* d_ws, size_t ws_size,
                              hipStream_t stream) {
    const float* x          = (const float*)d_in[0];
    const float* base_w     = (const float*)d_in[1];
    const float* base_b     = (const float*)d_in[2];
    const float* base_scale = (const float*)d_in[3];
    const float* wconv_w    = (const float*)d_in[4]; // (3, 384, 25)
    const float* wscale     = (const float*)d_in[5]; // (3, 384)
    float* out = (float*)d_out;
    unsigned* rec1 = (unsigned*)d_ws;   // (B*C,112,56) h2 dwords

    const int z = BB * CC;

    // levels 1+2 + reconstruction; writes rec1 only
    levels_fused2<<<z, 512, 0, stream>>>(
        x, rec1,
        wconv_w + 1 * 384 * 25, wscale + 1 * 384,
        wconv_w + 2 * 384 * 25, wscale + 2 * 384);
    // final: base conv + L0 haar+conv + combine with rec1 (packed cv)
    final_fused_v11<<<dim3(4, 4, z), 256, 0, stream>>>(
        x, base_w, base_b, base_scale,
        wconv_w + 0 * 384 * 25, wscale + 0 * 384, rec1, out);
}